// Round 3
// baseline (2827.082 us; speedup 1.0000x reference)
//
#include <hip/hip_runtime.h>

typedef unsigned short u16;
typedef __attribute__((ext_vector_type(8))) short s16x8;
typedef __attribute__((ext_vector_type(4))) float f32x4;

#define N_CLLN 120000
#define B_CLLN 200
#define NPG    600
#define E_CLLN 1200000
#define N_MOLN 64
#define E_MOLN 256
#define N_BION 19000
#define E_BION 600000
#define HDIM   200
#define NT     13   // 13 * 16 = 208 >= 200 output cols

__device__ __forceinline__ float b2f(u16 u){ return __uint_as_float(((unsigned)u)<<16); }
__device__ __forceinline__ u16 f2b(float f){
  unsigned x = __float_as_uint(f);
  return (u16)((x + 0x7fffu + ((x>>16)&1u)) >> 16);
}

// ---------- degree / norm ----------
__global__ void deg_count(const int* __restrict__ dst, float* __restrict__ deg, int E){
  int i = blockIdx.x*blockDim.x + threadIdx.x;
  int st = gridDim.x*blockDim.x;
  for (; i < E; i += st) unsafeAtomicAdd(&deg[dst[i]], 1.0f);
}
__global__ void deg_to_dinv(float* __restrict__ d, int N){
  int i = blockIdx.x*blockDim.x + threadIdx.x;
  if (i < N) d[i] = rsqrtf(d[i] + 1.0f);
}

// ---------- B-operand pre-pack (fp32 W -> bf16 MFMA fragment order) ----------
// lane l of tile (kk,nt) holds B[kk*32 + 8*(l>>4) + e][nt*16 + (l&15)], e=0..7
__global__ void pack_w(const float* __restrict__ W, u16* __restrict__ Bp, int K, int Ksteps){
  int idx = blockIdx.x*blockDim.x + threadIdx.x;
  int total = Ksteps*NT*64;
  if (idx >= total) return;
  int l  = idx & 63;
  int nt = (idx >> 6) % NT;
  int kk = idx / (64*NT);
  int n  = nt*16 + (l & 15);
  int k0 = kk*32 + (l>>4)*8;
  u16 v[8];
#pragma unroll
  for (int e=0;e<8;e++){
    int k = k0 + e;
    v[e] = (k < K && n < HDIM) ? f2b(W[(size_t)k*HDIM + n]) : (u16)0;
  }
#pragma unroll
  for (int e=0;e<8;e++) Bp[(size_t)idx*8 + e] = v[e];
}

// ---------- MFMA GEMM: Out[M,200](bf16) = A[M,Kact] @ Wpacked ----------
// AF32=1: A is fp32 (converted on the fly); AF32=0: A is bf16.
template<int AF32>
__global__ __launch_bounds__(256) void gemm_mfma(
    const void* __restrict__ Av, const u16* __restrict__ Bp,
    u16* __restrict__ Out, int M, int Kact, int Ksteps)
{
  const int w  = threadIdx.x >> 6;
  const int l  = threadIdx.x & 63;
  const int lm = l & 15;
  const int kg = l >> 4;
  int arow = blockIdx.x*64 + w*16 + lm;
  int rc = arow < M ? arow : 0;
  const float* ArowF = (const float*)Av + (size_t)rc * Kact;
  const u16*   ArowB = (const u16*)Av   + (size_t)rc * Kact;
  f32x4 fz = {0.f,0.f,0.f,0.f};
  f32x4 acc[NT];
#pragma unroll
  for (int t=0;t<NT;t++) acc[t] = fz;
  s16x8 az = {0,0,0,0,0,0,0,0};
  for (int kk=0; kk<Ksteps; ++kk){
    int k0 = kk*32 + kg*8;
    s16x8 a = az;
    if (k0 < Kact){
      if (AF32){
        f32x4 v0 = *(const f32x4*)(ArowF + k0);
        f32x4 v1 = *(const f32x4*)(ArowF + k0 + 4);
#pragma unroll
        for (int e=0;e<4;e++){ a[e] = (short)f2b(v0[e]); a[e+4] = (short)f2b(v1[e]); }
      } else {
        a = *(const s16x8*)(ArowB + k0);
      }
    }
    const u16* bp = Bp + ((size_t)kk*NT*64 + l)*8;
#pragma unroll
    for (int t=0;t<NT;t++){
      s16x8 b = *(const s16x8*)(bp + t*512);
      acc[t] = __builtin_amdgcn_mfma_f32_16x16x32_bf16(a, b, acc[t], 0, 0, 0);
    }
  }
  int orow = blockIdx.x*64 + w*16 + kg*4;   // C/D: col = lane&15, row = (lane>>4)*4 + j
#pragma unroll
  for (int t=0;t<NT;t++){
    int c = t*16 + lm;
    if (c < HDIM){
#pragma unroll
      for (int j=0;j<4;j++){
        int r = orow + j;
        if (r < M) Out[(size_t)r*HDIM + c] = f2b(acc[t][j]);
      }
    }
  }
}

// ---------- GCN aggregation ----------
__global__ void agg_init(const u16* __restrict__ t, const float* __restrict__ dinv,
                         float* __restrict__ G, int M){
  int i = blockIdx.x*blockDim.x + threadIdx.x;
  if (i >= M*HDIM) return;
  int r = i / HDIM;
  float dv = dinv[r];
  G[i] = b2f(t[i]) * dv * dv;   // self-loop term
}

__global__ __launch_bounds__(256) void agg_edges(
    const u16* __restrict__ t, const float* __restrict__ dinv,
    float* __restrict__ G, const int* __restrict__ src, const int* __restrict__ dst, int E)
{
  int wid = (blockIdx.x*blockDim.x + threadIdx.x) >> 6;
  int l = threadIdx.x & 63;
  int nw = (gridDim.x*blockDim.x) >> 6;
  for (int e = wid; e < E; e += nw){
    int s = src[e], d = dst[e];
    float wt = dinv[s]*dinv[d];
    const u16* ts = t + (size_t)s*HDIM;
    float* gd = G + (size_t)d*HDIM;
#pragma unroll
    for (int i=0;i<3;i++){
      int c = l + 64*i;
      unsafeAtomicAdd(gd + c, b2f(ts[c]) * wt);
    }
    if (l < HDIM - 192){
      int c = l + 192;
      unsafeAtomicAdd(gd + c, b2f(ts[c]) * wt);
    }
  }
}

__global__ void relu_bias(const float* __restrict__ G, const float* __restrict__ bias,
                          u16* __restrict__ out, int M){
  int i = blockIdx.x*blockDim.x + threadIdx.x;
  if (i >= M*HDIM) return;
  float v = G[i] + bias[i % HDIM];
  out[i] = f2b(v > 0.f ? v : 0.f);
}

// ---------- cll pooling + linear ----------
__global__ void pool_kernel(const u16* __restrict__ h, float* __restrict__ pooled){
  int b = blockIdx.x; int c = threadIdx.x;
  if (c >= HDIM) return;
  float s = 0.f;
  const u16* p = h + (size_t)b*NPG*HDIM + c;
  for (int r=0;r<NPG;r++) s += b2f(p[(size_t)r*HDIM]);
  pooled[b*HDIM + c] = s * (1.0f/NPG);
}

__global__ void xc_kernel(const float* __restrict__ pooled, const float* __restrict__ Wlc,
                          const float* __restrict__ blc, float* __restrict__ xc){
  __shared__ float p[HDIM];
  int b = blockIdx.x, j = threadIdx.x;   // 256 threads, 256 out cols
  if (j < HDIM) p[j] = pooled[b*HDIM + j];
  __syncthreads();
  float s = blc[j];
  for (int k=0;k<HDIM;k++) s += p[k]*Wlc[(size_t)k*256 + j];
  xc[(size_t)b*256 + j] = s;
}

// ---------- mol branch (all fp32) ----------
__global__ void mol_agg(const float* __restrict__ x, const int* __restrict__ src,
                        const int* __restrict__ dst, float* __restrict__ a, int E, int F){
  int idx = blockIdx.x*blockDim.x + threadIdx.x;
  if (idx >= E*F) return;
  int e = idx / F, f = idx % F;
  unsafeAtomicAdd(&a[dst[e]*F + f], x[(size_t)src[e]*F + f]);
}
__global__ void mol_l1(const float* __restrict__ x, const float* __restrict__ a1,
                       const float* __restrict__ Wrel, const float* __restrict__ brel,
                       const float* __restrict__ Wroot, float* __restrict__ m1){
  int idx = blockIdx.x*blockDim.x + threadIdx.x;
  if (idx >= N_MOLN*HDIM) return;
  int i = idx / HDIM, c = idx % HDIM;
  float s = brel[c];
  for (int k=0;k<64;k++){
    s += a1[i*64+k]*Wrel[k*HDIM+c];
    s += x[i*64+k]*Wroot[k*HDIM+c];
  }
  m1[idx] = fmaxf(s, 0.f);
}
__global__ void mol_l2(const float* __restrict__ m1, const float* __restrict__ a2,
                       const float* __restrict__ Wrel2, const float* __restrict__ brel2,
                       const float* __restrict__ Wroot2, float* __restrict__ colsum){
  int idx = blockIdx.x*blockDim.x + threadIdx.x;
  if (idx >= N_MOLN*HDIM) return;
  int i = idx / HDIM, c = idx % HDIM;
  float s = brel2[c];
  for (int k=0;k<HDIM;k++){
    s += a2[i*HDIM+k]*Wrel2[k*HDIM+c] + m1[i*HDIM+k]*Wroot2[k*HDIM+c];
  }
  s = fmaxf(s, 0.f);
  unsafeAtomicAdd(&colsum[c], s*(1.0f/N_MOLN));
}
__global__ void mol_head(const float* __restrict__ colsum, const float* __restrict__ Wlm,
                         const float* __restrict__ blm, float* __restrict__ xm){
  int j = threadIdx.x;
  if (j >= 128) return;
  float s = blm[j];
  for (int c=0;c<HDIM;c++) s += colsum[c]*Wlm[c*128+j];
  xm[j] = s;
}

// ---------- bio tail: only last node's layer-2 row ----------
__global__ void bio_last(const u16* __restrict__ t2, const float* __restrict__ dinv,
                         const int* __restrict__ src, const int* __restrict__ dst,
                         float* __restrict__ acc, int E, int last){
  int idx = blockIdx.x*blockDim.x + threadIdx.x;
  int st = gridDim.x*blockDim.x;
  for (int e = idx; e < E; e += st){
    if (dst[e] == last){
      int s = src[e];
      float wt = dinv[s]*dinv[last];
      const u16* ts = t2 + (size_t)s*HDIM;
      for (int c=0;c<HDIM;c++) unsafeAtomicAdd(&acc[c], b2f(ts[c])*wt);
    }
  }
}
__global__ void bio_head(const float* __restrict__ acc, const u16* __restrict__ t2,
                         const float* __restrict__ dinv, const float* __restrict__ bb2,
                         const float* __restrict__ Wlb, const float* __restrict__ blb,
                         float* __restrict__ xb, int last){
  __shared__ float v[HDIM];
  int tid = threadIdx.x;   // 256
  if (tid < HDIM){
    float dv = dinv[last];
    float s = acc[tid] + b2f(t2[(size_t)last*HDIM + tid])*dv*dv + bb2[tid];
    v[tid] = fmaxf(s, 0.f);
  }
  __syncthreads();
  if (tid < 128){
    float s = blb[tid];
    for (int c=0;c<HDIM;c++) s += v[c]*Wlb[c*128+tid];
    xb[tid] = s;
  }
}

// ---------- bilinear score ----------
__global__ void score_kernel(const float* __restrict__ xc, const float* __restrict__ W,
                             const float* __restrict__ bias, const float* __restrict__ xm,
                             const float* __restrict__ xb, float* __restrict__ out){
  __shared__ float xd[256];
  __shared__ float u[256];
  int tid = threadIdx.x;   // 256
  xd[tid] = (tid < 128) ? xm[tid] : xb[tid-128];
  __syncthreads();
  float s = 0.f;
  for (int j=0;j<256;j++) s += W[(size_t)tid*256 + j]*xd[j];
  u[tid] = s;
  __syncthreads();
  if (tid < B_CLLN){
    float sc = bias[0];
    const float* xr = xc + (size_t)tid*256;
    for (int i=0;i<256;i++) sc += xr[i]*u[i];
    out[tid] = sc;
  }
}

extern "C" void kernel_launch(void* const* d_in, const int* in_sizes, int n_in,
                              void* d_out, int out_size, void* d_ws, size_t ws_size,
                              hipStream_t stream) {
  const float* x_cll = (const float*)d_in[0];
  const float* x_mol = (const float*)d_in[1];
  const float* x_bio = (const float*)d_in[2];
  const int* e_cll = (const int*)d_in[3];
  const int* e_mol = (const int*)d_in[5];
  const int* e_bio = (const int*)d_in[6];
  const float *Wc1=(const float*)d_in[7],  *bc1=(const float*)d_in[8];
  const float *Wc2=(const float*)d_in[9],  *bc2=(const float*)d_in[10];
  const float *Wlc=(const float*)d_in[11], *blc=(const float*)d_in[12];
  const float *Wrel1=(const float*)d_in[13],*brel1=(const float*)d_in[14],*Wroot1=(const float*)d_in[15];
  const float *Wrel2=(const float*)d_in[16],*brel2=(const float*)d_in[17],*Wroot2=(const float*)d_in[18];
  const float *Wlm=(const float*)d_in[19], *blm=(const float*)d_in[20];
  const float *Wb1=(const float*)d_in[21], *bb1=(const float*)d_in[22];
  const float *Wb2=(const float*)d_in[23], *bb2=(const float*)d_in[24];
  const float *Wlb=(const float*)d_in[25], *blb=(const float*)d_in[26];
  const float *Wbl=(const float*)d_in[27], *bias=(const float*)d_in[28];
  float* out = (float*)d_out;

  char* ws = (char*)d_ws;
  size_t o = 0;
  auto alloc = [&](size_t bytes)->char*{
    char* p = ws + o;
    o = (o + bytes + 255) & ~(size_t)255;
    return p;
  };
  float* G     = (float*)alloc((size_t)N_CLLN*HDIM*4);   // 96 MB f32 accumulator
  u16*   BUF1  = (u16*)  alloc((size_t)N_CLLN*HDIM*2);   // 48 MB bf16
  u16*   BUF2  = (u16*)  alloc((size_t)N_CLLN*HDIM*2);   // 48 MB bf16
  float* dinvC = (float*)alloc((size_t)N_CLLN*4);
  float* dinvB = (float*)alloc((size_t)N_BION*4);
  float* pooled= (float*)alloc((size_t)B_CLLN*HDIM*4);
  float* xc    = (float*)alloc((size_t)B_CLLN*256*4);
  float* a1    = (float*)alloc((size_t)N_MOLN*64*4);
  float* m1    = (float*)alloc((size_t)N_MOLN*HDIM*4);
  float* a2    = (float*)alloc((size_t)N_MOLN*HDIM*4);
  float* colsum= (float*)alloc(HDIM*4);
  float* xm    = (float*)alloc(128*4);
  float* xb    = (float*)alloc(128*4);
  float* bacc  = (float*)alloc(HDIM*4);
  u16* Pc1 = (u16*)alloc((size_t)4*NT*64*8*2);
  u16* Pc2 = (u16*)alloc((size_t)7*NT*64*8*2);
  u16* Pb1 = (u16*)alloc((size_t)4*NT*64*8*2);
  u16* Pb2 = (u16*)alloc((size_t)7*NT*64*8*2);
  if (o > ws_size) return;   // scratch too small; bail deterministically
  (void)in_sizes; (void)n_in; (void)out_size;

  // zero accumulators
  hipMemsetAsync(dinvC, 0, (size_t)N_CLLN*4, stream);
  hipMemsetAsync(dinvB, 0, (size_t)N_BION*4, stream);
  hipMemsetAsync(a1, 0, (size_t)N_MOLN*64*4, stream);
  hipMemsetAsync(a2, 0, (size_t)N_MOLN*HDIM*4, stream);
  hipMemsetAsync(colsum, 0, HDIM*4, stream);
  hipMemsetAsync(bacc, 0, HDIM*4, stream);

  // pack weights
  pack_w<<<(4*NT*64+255)/256, 256, 0, stream>>>(Wc1, Pc1, 128, 4);
  pack_w<<<(7*NT*64+255)/256, 256, 0, stream>>>(Wc2, Pc2, 200, 7);
  pack_w<<<(4*NT*64+255)/256, 256, 0, stream>>>(Wb1, Pb1, 128, 4);
  pack_w<<<(7*NT*64+255)/256, 256, 0, stream>>>(Wb2, Pb2, 200, 7);

  // degrees
  deg_count<<<4096, 256, 0, stream>>>(e_cll + E_CLLN, dinvC, E_CLLN);
  deg_to_dinv<<<(N_CLLN+255)/256, 256, 0, stream>>>(dinvC, N_CLLN);
  deg_count<<<2048, 256, 0, stream>>>(e_bio + E_BION, dinvB, E_BION);
  deg_to_dinv<<<(N_BION+255)/256, 256, 0, stream>>>(dinvB, N_BION);

  const int gcll  = (N_CLLN+63)/64;
  const int gbio  = (N_BION+63)/64;
  const int ecll  = (N_CLLN*HDIM+255)/256;
  const int ebio  = (N_BION*HDIM+255)/256;

  // ---- cll layer 1 ----
  gemm_mfma<1><<<gcll, 256, 0, stream>>>(x_cll, Pc1, BUF1, N_CLLN, 128, 4);
  agg_init<<<ecll, 256, 0, stream>>>(BUF1, dinvC, G, N_CLLN);
  agg_edges<<<8192, 256, 0, stream>>>(BUF1, dinvC, G, e_cll, e_cll + E_CLLN, E_CLLN);
  relu_bias<<<ecll, 256, 0, stream>>>(G, bc1, BUF2, N_CLLN);
  // ---- cll layer 2 ----
  gemm_mfma<0><<<gcll, 256, 0, stream>>>(BUF2, Pc2, BUF1, N_CLLN, 200, 7);
  agg_init<<<ecll, 256, 0, stream>>>(BUF1, dinvC, G, N_CLLN);
  agg_edges<<<8192, 256, 0, stream>>>(BUF1, dinvC, G, e_cll, e_cll + E_CLLN, E_CLLN);
  relu_bias<<<ecll, 256, 0, stream>>>(G, bc2, BUF2, N_CLLN);
  // ---- pool + linear ----
  pool_kernel<<<B_CLLN, 256, 0, stream>>>(BUF2, pooled);
  xc_kernel<<<B_CLLN, 256, 0, stream>>>(pooled, Wlc, blc, xc);

  // ---- bio layer 1 ----
  gemm_mfma<1><<<gbio, 256, 0, stream>>>(x_bio, Pb1, BUF1, N_BION, 128, 4);
  agg_init<<<ebio, 256, 0, stream>>>(BUF1, dinvB, G, N_BION);
  agg_edges<<<4096, 256, 0, stream>>>(BUF1, dinvB, G, e_bio, e_bio + E_BION, E_BION);
  relu_bias<<<ebio, 256, 0, stream>>>(G, bb1, BUF2, N_BION);
  // ---- bio layer 2 (only last node's aggregation needed) ----
  gemm_mfma<0><<<gbio, 256, 0, stream>>>(BUF2, Pb2, BUF1, N_BION, 200, 7);
  bio_last<<<2048, 256, 0, stream>>>(BUF1, dinvB, e_bio, e_bio + E_BION, bacc, E_BION, N_BION-1);
  bio_head<<<1, 256, 0, stream>>>(bacc, BUF1, dinvB, bb2, Wlb, blb, xb, N_BION-1);

  // ---- mol branch ----
  mol_agg<<<(E_MOLN*64+255)/256, 256, 0, stream>>>(x_mol, e_mol, e_mol + E_MOLN, a1, E_MOLN, 64);
  mol_l1<<<(N_MOLN*HDIM+255)/256, 256, 0, stream>>>(x_mol, a1, Wrel1, brel1, Wroot1, m1);
  mol_agg<<<(E_MOLN*HDIM+255)/256, 256, 0, stream>>>(m1, e_mol, e_mol + E_MOLN, a2, E_MOLN, HDIM);
  mol_l2<<<(N_MOLN*HDIM+255)/256, 256, 0, stream>>>(m1, a2, Wrel2, brel2, Wroot2, colsum);
  mol_head<<<1, 128, 0, stream>>>(colsum, Wlm, blm, xm);

  // ---- score ----
  score_kernel<<<1, 256, 0, stream>>>(xc, Wbl, bias, xm, xb, out);
}

// Round 4
// 954.797 us; speedup vs baseline: 2.9609x; 2.9609x over previous
//
#include <hip/hip_runtime.h>

typedef unsigned short u16;
typedef __attribute__((ext_vector_type(8))) short s16x8;
typedef __attribute__((ext_vector_type(4))) float f32x4;

#define N_CLLN 120000
#define B_CLLN 200
#define NPG    600
#define E_CLLN 1200000
#define N_MOLN 64
#define E_MOLN 256
#define N_BION 19000
#define E_BION 600000
#define HDIM   200
#define NT     13   // 13 * 16 = 208 >= 200 output cols

__device__ __forceinline__ float b2f(u16 u){ return __uint_as_float(((unsigned)u)<<16); }
__device__ __forceinline__ u16 f2b(float f){
  unsigned x = __float_as_uint(f);
  return (u16)((x + 0x7fffu + ((x>>16)&1u)) >> 16);
}

// ================= CSR build =================
__global__ void hist_kernel(const int* __restrict__ dst, int* __restrict__ cnt, int E){
  int i = blockIdx.x*blockDim.x + threadIdx.x;
  if (i < E) atomicAdd(&cnt[dst[i]], 1);
}
__global__ void make_dinv(const int* __restrict__ cnt, float* __restrict__ dinv, int N){
  int i = blockIdx.x*blockDim.x + threadIdx.x;
  if (i < N) dinv[i] = rsqrtf((float)cnt[i] + 1.0f);   // +1 self loop
}
// two-level exclusive scan: 1024 elems per block
__global__ void scan1(const int* __restrict__ cnt, int* __restrict__ rows,
                      int* __restrict__ bsum, int N){
  __shared__ int sh[256];
  int b = blockIdx.x, t = threadIdx.x;
  int base = b*1024 + t*4;
  int v[4]; int s = 0;
#pragma unroll
  for (int i=0;i<4;i++){ int idx = base+i; v[i] = (idx<N)?cnt[idx]:0; s += v[i]; }
  sh[t] = s; __syncthreads();
  for (int off=1; off<256; off<<=1){
    int x = (t>=off)? sh[t-off] : 0; __syncthreads();
    sh[t] += x; __syncthreads();
  }
  int run = (t==0)? 0 : sh[t-1];
#pragma unroll
  for (int i=0;i<4;i++){ int idx = base+i; if (idx<N) rows[idx] = run; run += v[i]; }
  if (t==255) bsum[b] = sh[255];
}
__global__ void scan2(int* __restrict__ bsum, int nb){
  __shared__ int sh[256];
  int t = threadIdx.x;
  sh[t] = (t<nb)? bsum[t] : 0; __syncthreads();
  for (int off=1; off<256; off<<=1){
    int x = (t>=off)? sh[t-off] : 0; __syncthreads();
    sh[t] += x; __syncthreads();
  }
  if (t<nb) bsum[t] = (t==0)? 0 : sh[t-1];
}
__global__ void scan3(int* __restrict__ rows, const int* __restrict__ bsum, int N){
  int i = blockIdx.x*blockDim.x + threadIdx.x;
  if (i<N) rows[i] += bsum[i>>10];
}
__global__ void csr_scatter(const int* __restrict__ src, const int* __restrict__ dst,
                            const int* __restrict__ rows, int* __restrict__ cur,
                            int* __restrict__ csr, int E){
  int e = blockIdx.x*blockDim.x + threadIdx.x;
  if (e >= E) return;
  int d = dst[e];
  int p = atomicAdd(&cur[d], 1);
  csr[rows[d] + p] = src[e];
}

// ================= fused GCN aggregate (gather) + bias + relu =================
// one wave per destination node; bf16 in, bf16 out
__global__ __launch_bounds__(256) void gcn_gather(
    const u16* __restrict__ t, const float* __restrict__ dinv,
    const int* __restrict__ rows, const int* __restrict__ csr,
    const float* __restrict__ bias, u16* __restrict__ out, int N, int E)
{
  int wid = (blockIdx.x*blockDim.x + threadIdx.x) >> 6;
  int l = threadIdx.x & 63;
  if (wid >= N) return;
  int d = wid;
  float dv = dinv[d];
  int e0 = rows[d];
  int e1 = (d+1 < N) ? rows[d+1] : E;
  const u16* td = t + (size_t)d*HDIM;
  float selfw = dv*dv;
  float acc0 = b2f(td[l      ])*selfw;
  float acc1 = b2f(td[l + 64 ])*selfw;
  float acc2 = b2f(td[l + 128])*selfw;
  float acc3 = (l<8) ? b2f(td[l + 192])*selfw : 0.f;
  for (int e=e0; e<e1; ++e){
    int s = csr[e];
    float wt = dinv[s]*dv;
    const u16* ts = t + (size_t)s*HDIM;
    acc0 += b2f(ts[l      ])*wt;
    acc1 += b2f(ts[l + 64 ])*wt;
    acc2 += b2f(ts[l + 128])*wt;
    if (l<8) acc3 += b2f(ts[l + 192])*wt;
  }
  u16* od = out + (size_t)d*HDIM;
  od[l      ] = f2b(fmaxf(acc0 + bias[l      ], 0.f));
  od[l + 64 ] = f2b(fmaxf(acc1 + bias[l + 64 ], 0.f));
  od[l + 128] = f2b(fmaxf(acc2 + bias[l + 128], 0.f));
  if (l<8) od[l + 192] = f2b(fmaxf(acc3 + bias[l + 192], 0.f));
}

// ================= B-operand pre-pack (fp32 W -> bf16 MFMA fragment order) =================
// lane l of tile (kk,nt) holds B[kk*32 + 8*(l>>4) + e][nt*16 + (l&15)], e=0..7
__global__ void pack_w(const float* __restrict__ W, u16* __restrict__ Bp, int K, int Ksteps){
  int idx = blockIdx.x*blockDim.x + threadIdx.x;
  int total = Ksteps*NT*64;
  if (idx >= total) return;
  int l  = idx & 63;
  int nt = (idx >> 6) % NT;
  int kk = idx / (64*NT);
  int n  = nt*16 + (l & 15);
  int k0 = kk*32 + (l>>4)*8;
  u16 v[8];
#pragma unroll
  for (int e=0;e<8;e++){
    int k = k0 + e;
    v[e] = (k < K && n < HDIM) ? f2b(W[(size_t)k*HDIM + n]) : (u16)0;
  }
#pragma unroll
  for (int e=0;e<8;e++) Bp[(size_t)idx*8 + e] = v[e];
}

// ================= MFMA GEMM: Out[M,200](bf16) = A[M,Kact] @ Wpacked =================
template<int AF32>
__global__ __launch_bounds__(256) void gemm_mfma(
    const void* __restrict__ Av, const u16* __restrict__ Bp,
    u16* __restrict__ Out, int M, int Kact, int Ksteps)
{
  const int w  = threadIdx.x >> 6;
  const int l  = threadIdx.x & 63;
  const int lm = l & 15;
  const int kg = l >> 4;
  int arow = blockIdx.x*64 + w*16 + lm;
  int rc = arow < M ? arow : 0;
  const float* ArowF = (const float*)Av + (size_t)rc * Kact;
  const u16*   ArowB = (const u16*)Av   + (size_t)rc * Kact;
  f32x4 fz = {0.f,0.f,0.f,0.f};
  f32x4 acc[NT];
#pragma unroll
  for (int t=0;t<NT;t++) acc[t] = fz;
  s16x8 az = {0,0,0,0,0,0,0,0};
  for (int kk=0; kk<Ksteps; ++kk){
    int k0 = kk*32 + kg*8;
    s16x8 a = az;
    if (k0 < Kact){
      if (AF32){
        f32x4 v0 = *(const f32x4*)(ArowF + k0);
        f32x4 v1 = *(const f32x4*)(ArowF + k0 + 4);
#pragma unroll
        for (int e=0;e<4;e++){ a[e] = (short)f2b(v0[e]); a[e+4] = (short)f2b(v1[e]); }
      } else {
        a = *(const s16x8*)(ArowB + k0);
      }
    }
    const u16* bp = Bp + ((size_t)kk*NT*64 + l)*8;
#pragma unroll
    for (int t=0;t<NT;t++){
      s16x8 b = *(const s16x8*)(bp + t*512);
      acc[t] = __builtin_amdgcn_mfma_f32_16x16x32_bf16(a, b, acc[t], 0, 0, 0);
    }
  }
  int orow = blockIdx.x*64 + w*16 + kg*4;   // C/D: col = lane&15, row = (lane>>4)*4 + j
#pragma unroll
  for (int t=0;t<NT;t++){
    int c = t*16 + lm;
    if (c < HDIM){
#pragma unroll
      for (int j=0;j<4;j++){
        int r = orow + j;
        if (r < M) Out[(size_t)r*HDIM + c] = f2b(acc[t][j]);
      }
    }
  }
}

// ================= cll pooling + linear =================
__global__ void pool_kernel(const u16* __restrict__ h, float* __restrict__ pooled){
  int b = blockIdx.x; int c = threadIdx.x;
  if (c >= HDIM) return;
  float s = 0.f;
  const u16* p = h + (size_t)b*NPG*HDIM + c;
  for (int r=0;r<NPG;r++) s += b2f(p[(size_t)r*HDIM]);
  pooled[b*HDIM + c] = s * (1.0f/NPG);
}

__global__ void xc_kernel(const float* __restrict__ pooled, const float* __restrict__ Wlc,
                          const float* __restrict__ blc, float* __restrict__ xc){
  __shared__ float p[HDIM];
  int b = blockIdx.x, j = threadIdx.x;   // 256 threads, 256 out cols
  if (j < HDIM) p[j] = pooled[b*HDIM + j];
  __syncthreads();
  float s = blc[j];
  for (int k=0;k<HDIM;k++) s += p[k]*Wlc[(size_t)k*256 + j];
  xc[(size_t)b*256 + j] = s;
}

// ================= mol branch (all fp32) =================
__global__ void mol_agg(const float* __restrict__ x, const int* __restrict__ src,
                        const int* __restrict__ dst, float* __restrict__ a, int E, int F){
  int idx = blockIdx.x*blockDim.x + threadIdx.x;
  if (idx >= E*F) return;
  int e = idx / F, f = idx % F;
  unsafeAtomicAdd(&a[dst[e]*F + f], x[(size_t)src[e]*F + f]);
}
__global__ void mol_l1(const float* __restrict__ x, const float* __restrict__ a1,
                       const float* __restrict__ Wrel, const float* __restrict__ brel,
                       const float* __restrict__ Wroot, float* __restrict__ m1){
  int idx = blockIdx.x*blockDim.x + threadIdx.x;
  if (idx >= N_MOLN*HDIM) return;
  int i = idx / HDIM, c = idx % HDIM;
  float s = brel[c];
  for (int k=0;k<64;k++){
    s += a1[i*64+k]*Wrel[k*HDIM+c];
    s += x[i*64+k]*Wroot[k*HDIM+c];
  }
  m1[idx] = fmaxf(s, 0.f);
}
__global__ void mol_l2(const float* __restrict__ m1, const float* __restrict__ a2,
                       const float* __restrict__ Wrel2, const float* __restrict__ brel2,
                       const float* __restrict__ Wroot2, float* __restrict__ colsum){
  int idx = blockIdx.x*blockDim.x + threadIdx.x;
  if (idx >= N_MOLN*HDIM) return;
  int i = idx / HDIM, c = idx % HDIM;
  float s = brel2[c];
  for (int k=0;k<HDIM;k++){
    s += a2[i*HDIM+k]*Wrel2[k*HDIM+c] + m1[i*HDIM+k]*Wroot2[k*HDIM+c];
  }
  s = fmaxf(s, 0.f);
  unsafeAtomicAdd(&colsum[c], s*(1.0f/N_MOLN));
}
__global__ void mol_head(const float* __restrict__ colsum, const float* __restrict__ Wlm,
                         const float* __restrict__ blm, float* __restrict__ xm){
  int j = threadIdx.x;
  if (j >= 128) return;
  float s = blm[j];
  for (int c=0;c<HDIM;c++) s += colsum[c]*Wlm[c*128+j];
  xm[j] = s;
}

// ================= bio tail: CSR gather of last node + linear =================
__global__ void bio_head(const u16* __restrict__ t2, const float* __restrict__ dinv,
                         const int* __restrict__ rows, const int* __restrict__ csr,
                         const float* __restrict__ bb2, const float* __restrict__ Wlb,
                         const float* __restrict__ blb, float* __restrict__ xb, int N, int E){
  __shared__ float v[HDIM];
  int last = N-1;
  int tid = threadIdx.x;   // 256
  if (tid < HDIM){
    float dv = dinv[last];
    float acc = b2f(t2[(size_t)last*HDIM + tid])*dv*dv;
    int e1 = E;   // last node: bucket ends at E
    for (int e=rows[last]; e<e1; ++e){
      int s = csr[e];
      acc += b2f(t2[(size_t)s*HDIM + tid]) * dinv[s]*dv;
    }
    v[tid] = fmaxf(acc + bb2[tid], 0.f);
  }
  __syncthreads();
  if (tid < 128){
    float s = blb[tid];
    for (int c=0;c<HDIM;c++) s += v[c]*Wlb[c*128+tid];
    xb[tid] = s;
  }
}

// ================= bilinear score =================
__global__ void score_kernel(const float* __restrict__ xc, const float* __restrict__ W,
                             const float* __restrict__ bias, const float* __restrict__ xm,
                             const float* __restrict__ xb, float* __restrict__ out){
  __shared__ float xd[256];
  __shared__ float u[256];
  int tid = threadIdx.x;   // 256
  xd[tid] = (tid < 128) ? xm[tid] : xb[tid-128];
  __syncthreads();
  float s = 0.f;
  for (int j=0;j<256;j++) s += W[(size_t)tid*256 + j]*xd[j];
  u[tid] = s;
  __syncthreads();
  if (tid < B_CLLN){
    float sc = bias[0];
    const float* xr = xc + (size_t)tid*256;
    for (int i=0;i<256;i++) sc += xr[i]*u[i];
    out[tid] = sc;
  }
}

extern "C" void kernel_launch(void* const* d_in, const int* in_sizes, int n_in,
                              void* d_out, int out_size, void* d_ws, size_t ws_size,
                              hipStream_t stream) {
  const float* x_cll = (const float*)d_in[0];
  const float* x_mol = (const float*)d_in[1];
  const float* x_bio = (const float*)d_in[2];
  const int* e_cll = (const int*)d_in[3];
  const int* e_mol = (const int*)d_in[5];
  const int* e_bio = (const int*)d_in[6];
  const float *Wc1=(const float*)d_in[7],  *bc1=(const float*)d_in[8];
  const float *Wc2=(const float*)d_in[9],  *bc2=(const float*)d_in[10];
  const float *Wlc=(const float*)d_in[11], *blc=(const float*)d_in[12];
  const float *Wrel1=(const float*)d_in[13],*brel1=(const float*)d_in[14],*Wroot1=(const float*)d_in[15];
  const float *Wrel2=(const float*)d_in[16],*brel2=(const float*)d_in[17],*Wroot2=(const float*)d_in[18];
  const float *Wlm=(const float*)d_in[19], *blm=(const float*)d_in[20];
  const float *Wb1=(const float*)d_in[21], *bb1=(const float*)d_in[22];
  const float *Wb2=(const float*)d_in[23], *bb2=(const float*)d_in[24];
  const float *Wlb=(const float*)d_in[25], *blb=(const float*)d_in[26];
  const float *Wbl=(const float*)d_in[27], *bias=(const float*)d_in[28];
  float* out = (float*)d_out;

  char* ws = (char*)d_ws;
  size_t o = 0;
  auto alloc = [&](size_t bytes)->char*{
    char* p = ws + o;
    o = (o + bytes + 255) & ~(size_t)255;
    return p;
  };
  u16*   BUF1  = (u16*)  alloc((size_t)N_CLLN*HDIM*2);   // 48 MB bf16
  u16*   BUF2  = (u16*)  alloc((size_t)N_CLLN*HDIM*2);   // 48 MB bf16
  float* dinvC = (float*)alloc((size_t)N_CLLN*4);
  float* dinvB = (float*)alloc((size_t)N_BION*4);
  int*   cntC  = (int*)  alloc((size_t)N_CLLN*4);
  int*   rowC  = (int*)  alloc((size_t)N_CLLN*4);
  int*   curC  = (int*)  alloc((size_t)N_CLLN*4);
  int*   csrC  = (int*)  alloc((size_t)E_CLLN*4);
  int*   cntB  = (int*)  alloc((size_t)N_BION*4);
  int*   rowB  = (int*)  alloc((size_t)N_BION*4);
  int*   curB  = (int*)  alloc((size_t)N_BION*4);
  int*   csrB  = (int*)  alloc((size_t)E_BION*4);
  int*   bsumC = (int*)  alloc(256*4);
  int*   bsumB = (int*)  alloc(256*4);
  float* pooled= (float*)alloc((size_t)B_CLLN*HDIM*4);
  float* xc    = (float*)alloc((size_t)B_CLLN*256*4);
  float* a1    = (float*)alloc((size_t)N_MOLN*64*4);
  float* m1    = (float*)alloc((size_t)N_MOLN*HDIM*4);
  float* a2    = (float*)alloc((size_t)N_MOLN*HDIM*4);
  float* colsum= (float*)alloc(HDIM*4);
  float* xm    = (float*)alloc(128*4);
  float* xb    = (float*)alloc(128*4);
  u16* Pc1 = (u16*)alloc((size_t)4*NT*64*8*2);
  u16* Pc2 = (u16*)alloc((size_t)7*NT*64*8*2);
  u16* Pb1 = (u16*)alloc((size_t)4*NT*64*8*2);
  u16* Pb2 = (u16*)alloc((size_t)7*NT*64*8*2);
  if (o > ws_size) return;   // scratch too small; bail deterministically
  (void)in_sizes; (void)n_in; (void)out_size;

  // zero counters/accumulators
  hipMemsetAsync(cntC, 0, (size_t)N_CLLN*4, stream);
  hipMemsetAsync(curC, 0, (size_t)N_CLLN*4, stream);
  hipMemsetAsync(cntB, 0, (size_t)N_BION*4, stream);
  hipMemsetAsync(curB, 0, (size_t)N_BION*4, stream);
  hipMemsetAsync(a1, 0, (size_t)N_MOLN*64*4, stream);
  hipMemsetAsync(a2, 0, (size_t)N_MOLN*HDIM*4, stream);
  hipMemsetAsync(colsum, 0, HDIM*4, stream);

  // pack weights
  pack_w<<<(4*NT*64+255)/256, 256, 0, stream>>>(Wc1, Pc1, 128, 4);
  pack_w<<<(7*NT*64+255)/256, 256, 0, stream>>>(Wc2, Pc2, 200, 7);
  pack_w<<<(4*NT*64+255)/256, 256, 0, stream>>>(Wb1, Pb1, 128, 4);
  pack_w<<<(7*NT*64+255)/256, 256, 0, stream>>>(Wb2, Pb2, 200, 7);

  // ---- CSR build: cll ----
  const int* srcC = e_cll;  const int* dstC = e_cll + E_CLLN;
  hist_kernel<<<(E_CLLN+255)/256, 256, 0, stream>>>(dstC, cntC, E_CLLN);
  make_dinv<<<(N_CLLN+255)/256, 256, 0, stream>>>(cntC, dinvC, N_CLLN);
  scan1<<<(N_CLLN+1023)/1024, 256, 0, stream>>>(cntC, rowC, bsumC, N_CLLN);
  scan2<<<1, 256, 0, stream>>>(bsumC, (N_CLLN+1023)/1024);
  scan3<<<(N_CLLN+255)/256, 256, 0, stream>>>(rowC, bsumC, N_CLLN);
  csr_scatter<<<(E_CLLN+255)/256, 256, 0, stream>>>(srcC, dstC, rowC, curC, csrC, E_CLLN);
  // ---- CSR build: bio ----
  const int* srcB = e_bio;  const int* dstB = e_bio + E_BION;
  hist_kernel<<<(E_BION+255)/256, 256, 0, stream>>>(dstB, cntB, E_BION);
  make_dinv<<<(N_BION+255)/256, 256, 0, stream>>>(cntB, dinvB, N_BION);
  scan1<<<(N_BION+1023)/1024, 256, 0, stream>>>(cntB, rowB, bsumB, N_BION);
  scan2<<<1, 256, 0, stream>>>(bsumB, (N_BION+1023)/1024);
  scan3<<<(N_BION+255)/256, 256, 0, stream>>>(rowB, bsumB, N_BION);
  csr_scatter<<<(E_BION+255)/256, 256, 0, stream>>>(srcB, dstB, rowB, curB, csrB, E_BION);

  const int gcll  = (N_CLLN+63)/64;
  const int gbio  = (N_BION+63)/64;
  const int wcll  = (N_CLLN+3)/4;   // 4 waves per 256-block, one wave per node
  const int wbio  = (N_BION+3)/4;

  // ---- cll layer 1 ----
  gemm_mfma<1><<<gcll, 256, 0, stream>>>(x_cll, Pc1, BUF1, N_CLLN, 128, 4);
  gcn_gather<<<wcll, 256, 0, stream>>>(BUF1, dinvC, rowC, csrC, bc1, BUF2, N_CLLN, E_CLLN);
  // ---- cll layer 2 ----
  gemm_mfma<0><<<gcll, 256, 0, stream>>>(BUF2, Pc2, BUF1, N_CLLN, 200, 7);
  gcn_gather<<<wcll, 256, 0, stream>>>(BUF1, dinvC, rowC, csrC, bc2, BUF2, N_CLLN, E_CLLN);
  // ---- pool + linear ----
  pool_kernel<<<B_CLLN, 256, 0, stream>>>(BUF2, pooled);
  xc_kernel<<<B_CLLN, 256, 0, stream>>>(pooled, Wlc, blc, xc);

  // ---- bio layer 1 ----
  gemm_mfma<1><<<gbio, 256, 0, stream>>>(x_bio, Pb1, BUF1, N_BION, 128, 4);
  gcn_gather<<<wbio, 256, 0, stream>>>(BUF1, dinvB, rowB, csrB, bb1, BUF2, N_BION, E_BION);
  // ---- bio layer 2: gemm, then only last node's row via CSR ----
  gemm_mfma<0><<<gbio, 256, 0, stream>>>(BUF2, Pb2, BUF1, N_BION, 200, 7);
  bio_head<<<1, 256, 0, stream>>>(BUF1, dinvB, rowB, csrB, bb2, Wlb, blb, xb, N_BION, E_BION);

  // ---- mol branch ----
  mol_agg<<<(E_MOLN*64+255)/256, 256, 0, stream>>>(x_mol, e_mol, e_mol + E_MOLN, a1, E_MOLN, 64);
  mol_l1<<<(N_MOLN*HDIM+255)/256, 256, 0, stream>>>(x_mol, a1, Wrel1, brel1, Wroot1, m1);
  mol_agg<<<(E_MOLN*HDIM+255)/256, 256, 0, stream>>>(m1, e_mol, e_mol + E_MOLN, a2, E_MOLN, HDIM);
  mol_l2<<<(N_MOLN*HDIM+255)/256, 256, 0, stream>>>(m1, a2, Wrel2, brel2, Wroot2, colsum);
  mol_head<<<1, 128, 0, stream>>>(colsum, Wlm, blm, xm);

  // ---- score ----
  score_kernel<<<1, 256, 0, stream>>>(xc, Wbl, bias, xm, xb, out);
}

// Round 5
// 733.021 us; speedup vs baseline: 3.8568x; 1.3026x over previous
//
#include <hip/hip_runtime.h>

typedef unsigned short u16;
typedef __attribute__((ext_vector_type(8))) short s16x8;
typedef __attribute__((ext_vector_type(4))) float f32x4;

#define N_CLLN 120000
#define B_CLLN 200
#define NPG    600
#define E_CLLN 1200000
#define N_MOLN 64
#define E_MOLN 256
#define N_BION 19000
#define E_BION 600000
#define HDIM   200
#define HPAD   256   // padded row stride (512 B = 4 cache lines)
#define NT     13    // 13 * 16 = 208 >= 200 output cols

__device__ __forceinline__ float b2f(u16 u){ return __uint_as_float(((unsigned)u)<<16); }
__device__ __forceinline__ float u2f_lo(unsigned u){ return __uint_as_float(u<<16); }
__device__ __forceinline__ float u2f_hi(unsigned u){ return __uint_as_float(u & 0xFFFF0000u); }
__device__ __forceinline__ u16 f2b(float f){
  unsigned x = __float_as_uint(f);
  return (u16)((x + 0x7fffu + ((x>>16)&1u)) >> 16);
}

// ================= CSR build =================
__global__ void hist_kernel(const int* __restrict__ dst, int* __restrict__ cnt, int E){
  int i = blockIdx.x*blockDim.x + threadIdx.x;
  if (i < E) atomicAdd(&cnt[dst[i]], 1);
}
__global__ void make_dinv(const int* __restrict__ cnt, float* __restrict__ dinv, int N){
  int i = blockIdx.x*blockDim.x + threadIdx.x;
  if (i < N) dinv[i] = rsqrtf((float)cnt[i] + 1.0f);   // +1 self loop
}
__global__ void scan1(const int* __restrict__ cnt, int* __restrict__ rows,
                      int* __restrict__ bsum, int N){
  __shared__ int sh[256];
  int b = blockIdx.x, t = threadIdx.x;
  int base = b*1024 + t*4;
  int v[4]; int s = 0;
#pragma unroll
  for (int i=0;i<4;i++){ int idx = base+i; v[i] = (idx<N)?cnt[idx]:0; s += v[i]; }
  sh[t] = s; __syncthreads();
  for (int off=1; off<256; off<<=1){
    int x = (t>=off)? sh[t-off] : 0; __syncthreads();
    sh[t] += x; __syncthreads();
  }
  int run = (t==0)? 0 : sh[t-1];
#pragma unroll
  for (int i=0;i<4;i++){ int idx = base+i; if (idx<N) rows[idx] = run; run += v[i]; }
  if (t==255) bsum[b] = sh[255];
}
__global__ void scan2(int* __restrict__ bsum, int nb){
  __shared__ int sh[256];
  int t = threadIdx.x;
  sh[t] = (t<nb)? bsum[t] : 0; __syncthreads();
  for (int off=1; off<256; off<<=1){
    int x = (t>=off)? sh[t-off] : 0; __syncthreads();
    sh[t] += x; __syncthreads();
  }
  if (t<nb) bsum[t] = (t==0)? 0 : sh[t-1];
}
__global__ void scan3(int* __restrict__ rows, const int* __restrict__ bsum, int N){
  int i = blockIdx.x*blockDim.x + threadIdx.x;
  if (i<N) rows[i] += bsum[i>>10];
}
__global__ void csr_scatter(const int* __restrict__ src, const int* __restrict__ dst,
                            const int* __restrict__ rows, int* __restrict__ cur,
                            int* __restrict__ csr, int E){
  int e = blockIdx.x*blockDim.x + threadIdx.x;
  if (e >= E) return;
  int d = dst[e];
  int p = atomicAdd(&cur[d], 1);
  csr[rows[d] + p] = src[e];
}

// ===== fused GCN aggregate (gather over pre-scaled rows) + bias + relu =====
__global__ __launch_bounds__(256) void gcn_gather(
    const u16* __restrict__ t, const float* __restrict__ dinv,
    const int* __restrict__ rows, const int* __restrict__ csr,
    const float* __restrict__ bias, u16* __restrict__ out, int N, int E)
{
  int wid = (blockIdx.x*blockDim.x + threadIdx.x) >> 6;
  int l = threadIdx.x & 63;
  if (wid >= N) return;
  float dv = dinv[wid];
  int e0 = rows[wid];
  int e1 = (wid+1 < N) ? rows[wid+1] : E;
  const unsigned* base_u32 = (const unsigned*)t;
  const unsigned* sp = base_u32 + (size_t)wid*128 + l*2;
  unsigned sx = sp[0], sy = sp[1];
  float a0 = u2f_lo(sx), a1 = u2f_hi(sx), a2 = u2f_lo(sy), a3 = u2f_hi(sy);
  for (int b0 = e0; b0 < e1; b0 += 64){
    int n = e1 - b0;
    int cnt = n < 64 ? n : 64;
    int myv = (l < cnt) ? csr[b0 + l] : 0;
    int i = 0;
    for (; i+3 < cnt; i += 4){
      int s0 = __shfl(myv, i),   s1 = __shfl(myv, i+1);
      int s2 = __shfl(myv, i+2), s3 = __shfl(myv, i+3);
      const unsigned* p0 = base_u32 + (size_t)s0*128 + l*2;
      const unsigned* p1 = base_u32 + (size_t)s1*128 + l*2;
      const unsigned* p2 = base_u32 + (size_t)s2*128 + l*2;
      const unsigned* p3 = base_u32 + (size_t)s3*128 + l*2;
      unsigned x0 = p0[0], y0 = p0[1];
      unsigned x1 = p1[0], y1 = p1[1];
      unsigned x2 = p2[0], y2 = p2[1];
      unsigned x3 = p3[0], y3 = p3[1];
      a0 += u2f_lo(x0); a1 += u2f_hi(x0); a2 += u2f_lo(y0); a3 += u2f_hi(y0);
      a0 += u2f_lo(x1); a1 += u2f_hi(x1); a2 += u2f_lo(y1); a3 += u2f_hi(y1);
      a0 += u2f_lo(x2); a1 += u2f_hi(x2); a2 += u2f_lo(y2); a3 += u2f_hi(y2);
      a0 += u2f_lo(x3); a1 += u2f_hi(x3); a2 += u2f_lo(y3); a3 += u2f_hi(y3);
    }
    for (; i < cnt; ++i){
      int s0 = __shfl(myv, i);
      const unsigned* p0 = base_u32 + (size_t)s0*128 + l*2;
      unsigned x0 = p0[0], y0 = p0[1];
      a0 += u2f_lo(x0); a1 += u2f_hi(x0); a2 += u2f_lo(y0); a3 += u2f_hi(y0);
    }
  }
  unsigned rx = 0, ry = 0;
  if (l < 50){   // cols 4l..4l+3 < 200
    const f32x4 bv = *(const f32x4*)(bias + l*4);
    float r0 = fmaxf(a0*dv + bv[0], 0.f);
    float r1 = fmaxf(a1*dv + bv[1], 0.f);
    float r2 = fmaxf(a2*dv + bv[2], 0.f);
    float r3 = fmaxf(a3*dv + bv[3], 0.f);
    rx = (unsigned)f2b(r0) | ((unsigned)f2b(r1) << 16);
    ry = (unsigned)f2b(r2) | ((unsigned)f2b(r3) << 16);
  }
  unsigned* op = (unsigned*)out + (size_t)wid*128 + l*2;
  op[0] = rx; op[1] = ry;
}

// ================= B-operand pre-pack (fp32 W -> bf16 MFMA fragment order) =================
__global__ void pack_w(const float* __restrict__ W, u16* __restrict__ Bp, int K, int Ksteps){
  int idx = blockIdx.x*blockDim.x + threadIdx.x;
  int total = Ksteps*NT*64;
  if (idx >= total) return;
  int l  = idx & 63;
  int nt = (idx >> 6) % NT;
  int kk = idx / (64*NT);
  int n  = nt*16 + (l & 15);
  int k0 = kk*32 + (l>>4)*8;
  u16 v[8];
#pragma unroll
  for (int e=0;e<8;e++){
    int k = k0 + e;
    v[e] = (k < K && n < HDIM) ? f2b(W[(size_t)k*HDIM + n]) : (u16)0;
  }
#pragma unroll
  for (int e=0;e<8;e++) Bp[(size_t)idx*8 + e] = v[e];
}

// ===== MFMA GEMM: Out[M,HPAD](bf16, cols<208) = dinv[r] * (A[M,Kact] @ Wpacked) =====
template<int AF32>
__global__ __launch_bounds__(256) void gemm_mfma(
    const void* __restrict__ Av, const u16* __restrict__ Bp, const float* __restrict__ dinv,
    u16* __restrict__ Out, int M, int Kact, int Ksteps, int Astride)
{
  const int w  = threadIdx.x >> 6;
  const int l  = threadIdx.x & 63;
  const int lm = l & 15;
  const int kg = l >> 4;
  int arow = blockIdx.x*64 + w*16 + lm;
  int rc = arow < M ? arow : 0;
  const float* ArowF = (const float*)Av + (size_t)rc * Astride;
  const u16*   ArowB = (const u16*)Av   + (size_t)rc * Astride;
  f32x4 fz = {0.f,0.f,0.f,0.f};
  f32x4 acc[NT];
#pragma unroll
  for (int t=0;t<NT;t++) acc[t] = fz;
  s16x8 az = {0,0,0,0,0,0,0,0};
  for (int kk=0; kk<Ksteps; ++kk){
    int k0 = kk*32 + kg*8;
    s16x8 a = az;
    if (k0 < Kact){
      if (AF32){
        f32x4 v0 = *(const f32x4*)(ArowF + k0);
        f32x4 v1 = *(const f32x4*)(ArowF + k0 + 4);
#pragma unroll
        for (int e=0;e<4;e++){ a[e] = (short)f2b(v0[e]); a[e+4] = (short)f2b(v1[e]); }
      } else {
        a = *(const s16x8*)(ArowB + k0);
      }
    }
    const u16* bp = Bp + ((size_t)kk*NT*64 + l)*8;
#pragma unroll
    for (int t=0;t<NT;t++){
      s16x8 b = *(const s16x8*)(bp + t*512);
      acc[t] = __builtin_amdgcn_mfma_f32_16x16x32_bf16(a, b, acc[t], 0, 0, 0);
    }
  }
  int orow = blockIdx.x*64 + w*16 + kg*4;   // C/D: col = lane&15, row = (lane>>4)*4 + j
  float sc[4];
#pragma unroll
  for (int j=0;j<4;j++){ int r = orow + j; sc[j] = (r < M) ? dinv[r] : 0.f; }
#pragma unroll
  for (int t=0;t<NT;t++){
    int c = t*16 + lm;
#pragma unroll
    for (int j=0;j<4;j++){
      int r = orow + j;
      if (r < M) Out[(size_t)r*HPAD + c] = f2b(acc[t][j]*sc[j]);
    }
  }
}

// ================= cll pooling + linear =================
__global__ void pool_kernel(const u16* __restrict__ h, float* __restrict__ pooled){
  int b = blockIdx.x; int c = threadIdx.x;
  if (c >= HDIM) return;
  float s = 0.f;
  const u16* p = h + (size_t)b*NPG*HPAD + c;
  for (int r=0;r<NPG;r++) s += b2f(p[(size_t)r*HPAD]);
  pooled[b*HDIM + c] = s * (1.0f/NPG);
}

__global__ void xc_kernel(const float* __restrict__ pooled, const float* __restrict__ Wlc,
                          const float* __restrict__ blc, float* __restrict__ xc){
  __shared__ float p[HDIM];
  int b = blockIdx.x, j = threadIdx.x;   // 256 threads, 256 out cols
  if (j < HDIM) p[j] = pooled[b*HDIM + j];
  __syncthreads();
  float s = blc[j];
  for (int k=0;k<HDIM;k++) s += p[k]*Wlc[(size_t)k*256 + j];
  xc[(size_t)b*256 + j] = s;
}

// ================= mol branch (all fp32) =================
__global__ void mol_agg(const float* __restrict__ x, const int* __restrict__ src,
                        const int* __restrict__ dst, float* __restrict__ a, int E, int F){
  int idx = blockIdx.x*blockDim.x + threadIdx.x;
  if (idx >= E*F) return;
  int e = idx / F, f = idx % F;
  unsafeAtomicAdd(&a[dst[e]*F + f], x[(size_t)src[e]*F + f]);
}
__global__ void mol_l1(const float* __restrict__ x, const float* __restrict__ a1,
                       const float* __restrict__ Wrel, const float* __restrict__ brel,
                       const float* __restrict__ Wroot, float* __restrict__ m1){
  int idx = blockIdx.x*blockDim.x + threadIdx.x;
  if (idx >= N_MOLN*HDIM) return;
  int i = idx / HDIM, c = idx % HDIM;
  float s = brel[c];
  for (int k=0;k<64;k++){
    s += a1[i*64+k]*Wrel[k*HDIM+c];
    s += x[i*64+k]*Wroot[k*HDIM+c];
  }
  m1[idx] = fmaxf(s, 0.f);
}
__global__ void mol_l2(const float* __restrict__ m1, const float* __restrict__ a2,
                       const float* __restrict__ Wrel2, const float* __restrict__ brel2,
                       const float* __restrict__ Wroot2, float* __restrict__ colsum){
  int idx = blockIdx.x*blockDim.x + threadIdx.x;
  if (idx >= N_MOLN*HDIM) return;
  int i = idx / HDIM, c = idx % HDIM;
  float s = brel2[c];
  for (int k=0;k<HDIM;k++){
    s += a2[i*HDIM+k]*Wrel2[k*HDIM+c] + m1[i*HDIM+k]*Wroot2[k*HDIM+c];
  }
  s = fmaxf(s, 0.f);
  unsafeAtomicAdd(&colsum[c], s*(1.0f/N_MOLN));
}
__global__ void mol_head(const float* __restrict__ colsum, const float* __restrict__ Wlm,
                         const float* __restrict__ blm, float* __restrict__ xm){
  int j = threadIdx.x;
  if (j >= 128) return;
  float s = blm[j];
  for (int c=0;c<HDIM;c++) s += colsum[c]*Wlm[c*128+j];
  xm[j] = s;
}

// ===== bio tail: CSR gather of last node (pre-scaled rows) + linear =====
__global__ void bio_head(const u16* __restrict__ t2, const float* __restrict__ dinv,
                         const int* __restrict__ rows, const int* __restrict__ csr,
                         const float* __restrict__ bb2, const float* __restrict__ Wlb,
                         const float* __restrict__ blb, float* __restrict__ xb, int N, int E){
  __shared__ float v[HDIM];
  int last = N-1;
  int tid = threadIdx.x;   // 256
  if (tid < HDIM){
    float dv = dinv[last];
    float acc = b2f(t2[(size_t)last*HPAD + tid]);
    for (int e=rows[last]; e<E; ++e){
      int s = csr[e];
      acc += b2f(t2[(size_t)s*HPAD + tid]);
    }
    v[tid] = fmaxf(acc*dv + bb2[tid], 0.f);
  }
  __syncthreads();
  if (tid < 128){
    float s = blb[tid];
    for (int c=0;c<HDIM;c++) s += v[c]*Wlb[c*128+tid];
    xb[tid] = s;
  }
}

// ================= bilinear score =================
__global__ void score_kernel(const float* __restrict__ xc, const float* __restrict__ W,
                             const float* __restrict__ bias, const float* __restrict__ xm,
                             const float* __restrict__ xb, float* __restrict__ out){
  __shared__ float xd[256];
  __shared__ float u[256];
  int tid = threadIdx.x;   // 256
  xd[tid] = (tid < 128) ? xm[tid] : xb[tid-128];
  __syncthreads();
  float s = 0.f;
  for (int j=0;j<256;j++) s += W[(size_t)tid*256 + j]*xd[j];
  u[tid] = s;
  __syncthreads();
  if (tid < B_CLLN){
    float sc = bias[0];
    const float* xr = xc + (size_t)tid*256;
    for (int i=0;i<256;i++) sc += xr[i]*u[i];
    out[tid] = sc;
  }
}

extern "C" void kernel_launch(void* const* d_in, const int* in_sizes, int n_in,
                              void* d_out, int out_size, void* d_ws, size_t ws_size,
                              hipStream_t stream) {
  const float* x_cll = (const float*)d_in[0];
  const float* x_mol = (const float*)d_in[1];
  const float* x_bio = (const float*)d_in[2];
  const int* e_cll = (const int*)d_in[3];
  const int* e_mol = (const int*)d_in[5];
  const int* e_bio = (const int*)d_in[6];
  const float *Wc1=(const float*)d_in[7],  *bc1=(const float*)d_in[8];
  const float *Wc2=(const float*)d_in[9],  *bc2=(const float*)d_in[10];
  const float *Wlc=(const float*)d_in[11], *blc=(const float*)d_in[12];
  const float *Wrel1=(const float*)d_in[13],*brel1=(const float*)d_in[14],*Wroot1=(const float*)d_in[15];
  const float *Wrel2=(const float*)d_in[16],*brel2=(const float*)d_in[17],*Wroot2=(const float*)d_in[18];
  const float *Wlm=(const float*)d_in[19], *blm=(const float*)d_in[20];
  const float *Wb1=(const float*)d_in[21], *bb1=(const float*)d_in[22];
  const float *Wb2=(const float*)d_in[23], *bb2=(const float*)d_in[24];
  const float *Wlb=(const float*)d_in[25], *blb=(const float*)d_in[26];
  const float *Wbl=(const float*)d_in[27], *bias=(const float*)d_in[28];
  float* out = (float*)d_out;

  char* ws = (char*)d_ws;
  size_t o = 0;
  auto alloc = [&](size_t bytes)->char*{
    char* p = ws + o;
    o = (o + bytes + 255) & ~(size_t)255;
    return p;
  };
  u16*   BUF1  = (u16*)  alloc((size_t)N_CLLN*HPAD*2);   // 61 MB (padded rows)
  u16*   BUF2  = (u16*)  alloc((size_t)N_CLLN*HPAD*2);   // 61 MB
  float* dinvC = (float*)alloc((size_t)N_CLLN*4);
  float* dinvB = (float*)alloc((size_t)N_BION*4);
  int*   cntC  = (int*)  alloc((size_t)(2*N_CLLN+2*N_BION)*4);  // cnt/cur zero region
  int*   curC  = cntC + N_CLLN;
  int*   cntB  = curC + N_CLLN;
  int*   curB  = cntB + N_BION;
  int*   rowC  = (int*)  alloc((size_t)N_CLLN*4);
  int*   csrC  = (int*)  alloc((size_t)E_CLLN*4);
  int*   rowB  = (int*)  alloc((size_t)N_BION*4);
  int*   csrB  = (int*)  alloc((size_t)E_BION*4);
  int*   bsumC = (int*)  alloc(256*4);
  int*   bsumB = (int*)  alloc(256*4);
  float* pooled= (float*)alloc((size_t)B_CLLN*HDIM*4);
  float* xc    = (float*)alloc((size_t)B_CLLN*256*4);
  float* a1    = (float*)alloc((size_t)(N_MOLN*64 + N_MOLN*HDIM + HDIM)*4);  // zero region
  float* a2    = a1 + N_MOLN*64;
  float* colsum= a2 + N_MOLN*HDIM;
  float* m1    = (float*)alloc((size_t)N_MOLN*HDIM*4);
  float* xm    = (float*)alloc(128*4);
  float* xb    = (float*)alloc(128*4);
  u16* Pc1 = (u16*)alloc((size_t)4*NT*64*8*2);
  u16* Pc2 = (u16*)alloc((size_t)7*NT*64*8*2);
  u16* Pb1 = (u16*)alloc((size_t)4*NT*64*8*2);
  u16* Pb2 = (u16*)alloc((size_t)7*NT*64*8*2);
  if (o > ws_size) return;   // scratch too small; bail deterministically
  (void)in_sizes; (void)n_in; (void)out_size;

  hipMemsetAsync(cntC, 0, (size_t)(2*N_CLLN+2*N_BION)*4, stream);
  hipMemsetAsync(a1, 0, (size_t)(N_MOLN*64 + N_MOLN*HDIM + HDIM)*4, stream);

  // pack weights
  pack_w<<<(4*NT*64+255)/256, 256, 0, stream>>>(Wc1, Pc1, 128, 4);
  pack_w<<<(7*NT*64+255)/256, 256, 0, stream>>>(Wc2, Pc2, 200, 7);
  pack_w<<<(4*NT*64+255)/256, 256, 0, stream>>>(Wb1, Pb1, 128, 4);
  pack_w<<<(7*NT*64+255)/256, 256, 0, stream>>>(Wb2, Pb2, 200, 7);

  // ---- CSR build: cll ----
  const int* srcC = e_cll;  const int* dstC = e_cll + E_CLLN;
  hist_kernel<<<(E_CLLN+255)/256, 256, 0, stream>>>(dstC, cntC, E_CLLN);
  make_dinv<<<(N_CLLN+255)/256, 256, 0, stream>>>(cntC, dinvC, N_CLLN);
  scan1<<<(N_CLLN+1023)/1024, 256, 0, stream>>>(cntC, rowC, bsumC, N_CLLN);
  scan2<<<1, 256, 0, stream>>>(bsumC, (N_CLLN+1023)/1024);
  scan3<<<(N_CLLN+255)/256, 256, 0, stream>>>(rowC, bsumC, N_CLLN);
  csr_scatter<<<(E_CLLN+255)/256, 256, 0, stream>>>(srcC, dstC, rowC, curC, csrC, E_CLLN);
  // ---- CSR build: bio ----
  const int* srcB = e_bio;  const int* dstB = e_bio + E_BION;
  hist_kernel<<<(E_BION+255)/256, 256, 0, stream>>>(dstB, cntB, E_BION);
  make_dinv<<<(N_BION+255)/256, 256, 0, stream>>>(cntB, dinvB, N_BION);
  scan1<<<(N_BION+1023)/1024, 256, 0, stream>>>(cntB, rowB, bsumB, N_BION);
  scan2<<<1, 256, 0, stream>>>(bsumB, (N_BION+1023)/1024);
  scan3<<<(N_BION+255)/256, 256, 0, stream>>>(rowB, bsumB, N_BION);
  csr_scatter<<<(E_BION+255)/256, 256, 0, stream>>>(srcB, dstB, rowB, curB, csrB, E_BION);

  const int gcll  = (N_CLLN+63)/64;
  const int gbio  = (N_BION+63)/64;
  const int wcll  = (N_CLLN+3)/4;   // one wave per node, 4 waves/block
  const int wbio  = (N_BION+3)/4;

  // ---- cll layer 1 ----
  gemm_mfma<1><<<gcll, 256, 0, stream>>>(x_cll, Pc1, dinvC, BUF1, N_CLLN, 128, 4, 128);
  gcn_gather<<<wcll, 256, 0, stream>>>(BUF1, dinvC, rowC, csrC, bc1, BUF2, N_CLLN, E_CLLN);
  // ---- cll layer 2 ----
  gemm_mfma<0><<<gcll, 256, 0, stream>>>(BUF2, Pc2, dinvC, BUF1, N_CLLN, 200, 7, HPAD);
  gcn_gather<<<wcll, 256, 0, stream>>>(BUF1, dinvC, rowC, csrC, bc2, BUF2, N_CLLN, E_CLLN);
  // ---- pool + linear ----
  pool_kernel<<<B_CLLN, 256, 0, stream>>>(BUF2, pooled);
  xc_kernel<<<B_CLLN, 256, 0, stream>>>(pooled, Wlc, blc, xc);

  // ---- bio layer 1 ----
  gemm_mfma<1><<<gbio, 256, 0, stream>>>(x_bio, Pb1, dinvB, BUF1, N_BION, 128, 4, 128);
  gcn_gather<<<wbio, 256, 0, stream>>>(BUF1, dinvB, rowB, csrB, bb1, BUF2, N_BION, E_BION);
  // ---- bio layer 2: gemm (pre-scaled), then only last node's row via CSR ----
  gemm_mfma<0><<<gbio, 256, 0, stream>>>(BUF2, Pb2, dinvB, BUF1, N_BION, 200, 7, HPAD);
  bio_head<<<1, 256, 0, stream>>>(BUF1, dinvB, rowB, csrB, bb2, Wlb, blb, xb, N_BION, E_BION);

  // ---- mol branch ----
  mol_agg<<<(E_MOLN*64+255)/256, 256, 0, stream>>>(x_mol, e_mol, e_mol + E_MOLN, a1, E_MOLN, 64);
  mol_l1<<<(N_MOLN*HDIM+255)/256, 256, 0, stream>>>(x_mol, a1, Wrel1, brel1, Wroot1, m1);
  mol_agg<<<(E_MOLN*HDIM+255)/256, 256, 0, stream>>>(m1, e_mol, e_mol + E_MOLN, a2, E_MOLN, HDIM);
  mol_l2<<<(N_MOLN*HDIM+255)/256, 256, 0, stream>>>(m1, a2, Wrel2, brel2, Wroot2, colsum);
  mol_head<<<1, 128, 0, stream>>>(colsum, Wlm, blm, xm);

  // ---- score ----
  score_kernel<<<1, 256, 0, stream>>>(xc, Wbl, bias, xm, xb, out);
}